// Round 10
// baseline (409.784 us; speedup 1.0000x reference)
//
#include <hip/hip_runtime.h>
#include <math.h>

#define EPSD 1e-8
#define EPSF 1e-8f
#define TOLW 1e-5f
#define IMG_H 512
#define IMG_W 512
#define TEX_W 1024
#define TEX_H 1024
#define RCH 256    // triangles per compaction chunk
#define SPLIT 2    // triangle-dimension split per tile

// ---------------------------------------------------------------------------
// Kernel 1: project vertices in f64 -> vpixd (x_pix, y_pix, z_cam)
// ---------------------------------------------------------------------------
__global__ __launch_bounds__(256) void k_project(
    const float* __restrict__ v,
    const float* __restrict__ campos,
    const float* __restrict__ camrot,
    const float* __restrict__ focal,
    const float* __restrict__ princpt,
    double* __restrict__ vpixd,
    int N, int V) {
#pragma clang fp contract(off)
  int i = blockIdx.x * blockDim.x + threadIdx.x;
  if (i >= N * V) return;
  int n = i / V;
  const float* vv = v + (size_t)i * 3;
  double ax = (double)vv[0] - (double)campos[n * 3 + 0];
  double ay = (double)vv[1] - (double)campos[n * 3 + 1];
  double az = (double)vv[2] - (double)campos[n * 3 + 2];
  const float* R = camrot + (size_t)n * 9;
  double cx = ((double)R[0] * ax + (double)R[1] * ay) + (double)R[2] * az;
  double cy = ((double)R[3] * ax + (double)R[4] * ay) + (double)R[5] * az;
  double cz = ((double)R[6] * ax + (double)R[7] * ay) + (double)R[8] * az;
  double zz = fmax(cz, EPSD);
  double xd = cx / zz;
  double yd = cy / zz;
  const float* Fc = focal + (size_t)n * 4;
  double px = ((double)Fc[0] * xd + (double)Fc[1] * yd) + (double)princpt[n * 2 + 0];
  double py = ((double)Fc[2] * xd + (double)Fc[3] * yd) + (double)princpt[n * 2 + 1];
  vpixd[(size_t)i * 3 + 0] = px;
  vpixd[(size_t)i * 3 + 1] = py;
  vpixd[(size_t)i * 3 + 2] = cz;
}

// ---------------------------------------------------------------------------
// Kernel 2: per-triangle setup. Emits BOTH:
//  (a) exact f64 coeffs (R9 layout, used by the k_fix fallback):
//      T[0]=(EA0,EB0) T[1]=(EC0,EA1) T[2]=(EB1,EC1) T[3]=(EA2,EB2)
//      T[4]=(EC2,P)  T[5]=(Q,S)
//  (b) f32 filter pack (3 x float4):
//      q0=[fa0,fb0,fc0,fa1]  q1=[fb1,fc1,A2f,tz]  q2=[fp,fq,fs,idxf]
//      Edges commonly scaled by g=1/max_k(512(|EA_k|+|EB_k|)+|EC_k|) so the
//      f32 eval error of W is <= ~3.5e-6 absolute (TOLW=1e-5 covers it);
//      W2 = A2f - W0 - W1 via the sum identity sum(W)=g*area^2.
//      tz = 2e-6 * (512|P|+512|S|+|Q|) bounds the f32 zi error.
// ---------------------------------------------------------------------------
__global__ __launch_bounds__(256) void k_setup(
    const double* __restrict__ vpixd,
    const int* __restrict__ vi,
    double2* __restrict__ tri,
    float4* __restrict__ trif,
    float4* __restrict__ bbox,
    int N, int V, int F) {
#pragma clang fp contract(off)
  int i = blockIdx.x * blockDim.x + threadIdx.x;
  if (i >= N * F) return;
  int n = i / F;
  int f = i - n * F;
  int i0 = vi[f * 3 + 0], i1 = vi[f * 3 + 1], i2 = vi[f * 3 + 2];
  const double* p0 = vpixd + ((size_t)n * V + i0) * 3;
  const double* p1 = vpixd + ((size_t)n * V + i1) * 3;
  const double* p2 = vpixd + ((size_t)n * V + i2) * 3;
  double x0 = p0[0], y0 = p0[1], z0 = p0[2];
  double x1 = p1[0], y1 = p1[1], z1 = p1[2];
  double x2 = p2[0], y2 = p2[1], z2 = p2[2];
  double A0 = y2 - y1, B0 = x2 - x1;
  double A1 = y0 - y2, B1 = x0 - x2;
  double A2 = y1 - y0, B2 = x1 - x0;
  double area = (x2 - x0) * A2 - (y2 - y0) * B2;
  bool valid = (fabs(area) > EPSD) && (z0 > EPSD) && (z1 > EPSD) && (z2 > EPSD);
  double s = area;
  double EA0 = 0.0, EB0 = 0.0, EC0 = -1.0;
  double EA1 = 0.0, EB1 = 0.0, EC1 = -1.0;
  double EA2 = 0.0, EB2 = 0.0, EC2 = -1.0;
  double P = 0.0, Q = 0.0, S = 0.0;
  float4 f0v = make_float4(0.f, 0.f, -1.f, 0.f);
  float4 f1v = make_float4(0.f, -1.f, -3.f, 0.f);
  float4 f2v = make_float4(0.f, 0.f, 0.f, (float)f);
  if (valid) {
    EA0 = A0 * s; EB0 = -(B0 * s); EC0 = (y1 * B0 - x1 * A0) * s;
    EA1 = A1 * s; EB1 = -(B1 * s); EC1 = (y2 * B1 - x2 * A1) * s;
    EA2 = A2 * s; EB2 = -(B2 * s); EC2 = (y0 * B2 - x0 * A2) * s;
    double s2 = s * s;
    double R0 = 1.0 / (s2 * fmax(z0, EPSD));
    double R1 = 1.0 / (s2 * fmax(z1, EPSD));
    double R2 = 1.0 / (s2 * fmax(z2, EPSD));
    P = EA0 * R0 + EA1 * R1 + EA2 * R2;
    S = EB0 * R0 + EB1 * R1 + EB2 * R2;
    Q = EC0 * R0 + EC1 * R1 + EC2 * R2;
    double m0 = 512.0 * (fabs(EA0) + fabs(EB0)) + fabs(EC0);
    double m1 = 512.0 * (fabs(EA1) + fabs(EB1)) + fabs(EC1);
    double m2 = 512.0 * (fabs(EA2) + fabs(EB2)) + fabs(EC2);
    double g = 1.0 / fmax(m0, fmax(m1, m2));
    double D = 512.0 * (fabs(P) + fabs(S)) + fabs(Q);
    f0v = make_float4((float)(EA0 * g), (float)(EB0 * g), (float)(EC0 * g),
                      (float)(EA1 * g));
    f1v = make_float4((float)(EB1 * g), (float)(EC1 * g),
                      (float)(g * s2), (float)(2.0e-6 * D));
    f2v = make_float4((float)P, (float)Q, (float)S, (float)f);
  }
  double2* T = tri + (size_t)i * 6;
  T[0] = make_double2(EA0, EB0);
  T[1] = make_double2(EC0, EA1);
  T[2] = make_double2(EB1, EC1);
  T[3] = make_double2(EA2, EB2);
  T[4] = make_double2(EC2, P);
  T[5] = make_double2(Q, S);
  float4* Tf = trif + (size_t)i * 3;
  Tf[0] = f0v; Tf[1] = f1v; Tf[2] = f2v;
  float mnx = (float)fmin(x0, fmin(x1, x2));
  float mny = (float)fmin(y0, fmin(y1, y2));
  float mxx = (float)fmax(x0, fmax(x1, x2));
  float mxy = (float)fmax(y0, fmax(y1, y2));
  bbox[i] = make_float4(mnx, mny, mxx, mxy);
}

// ---------------------------------------------------------------------------
// Kernel 3: f32-filtered tiled rasterizer. 16x32-px tile / 2 px per thread,
// triangle-split (SPLIT=2). Per 256-triangle chunk: ordered ballot/prefix
// compaction of bbox survivors' f32 packs into LDS (3 b128/iter, was 7 DS
// instr — LDS pipe was the R9 bottleneck). Filter: strict/loose inside via
// min3(W) vs ±TOLW; zi compared with interval [zi±tz]; clean wins update,
// anything ambiguous sets the pixel flag (exact f64 re-resolution later).
// Outputs per split: bestZ (f32), bestTol (f32), enc = (idx+1)|flag<<30.
// ---------------------------------------------------------------------------
__global__ __launch_bounds__(256, 8) void k_raster(
    const float4* __restrict__ trif,
    const float4* __restrict__ bbox,
    float* __restrict__ zpart,
    float* __restrict__ tpart,
    int* __restrict__ ipart,
    int F) {
  __shared__ float4 s_tri[RCH * 3];    // 12288 B
  __shared__ int s_wcnt[4];
  int nz = blockIdx.z;
  int n = nz / SPLIT;
  int s = nz - n * SPLIT;
  int x = blockIdx.x * 16 + threadIdx.x;
  int yA = blockIdx.y * 32 + threadIdx.y;
  int yB = yA + 16;
  float px = (float)x;
  float pyA = (float)yA, pyB = (float)yB;
  float tminx = (float)(blockIdx.x * 16) - 0.5f;   // 0.5px guard band
  float tmaxx = tminx + 16.0f;
  float tminy = (float)(blockIdx.y * 32) - 0.5f;
  float tmaxy = tminy + 32.0f;
  int tid = threadIdx.y * 16 + threadIdx.x;
  int wid = tid >> 6, lane = tid & 63;
  float bA = EPSF, bB = EPSF;       // zi > EPS folded into strict->
  float btA = 0.0f, btB = 0.0f;
  int iA = -1, iB = -1;
  bool flA = false, flB = false;
  const float4* trin = trif + (size_t)n * F * 3;
  const float4* bbn = bbox + (size_t)n * F;
  int half = (F + SPLIT - 1) / SPLIT;
  int tbeg = s * half;
  int tend = min(F, tbeg + half);

  for (int c = tbeg; c < tend; c += RCH) {
    int t = c + tid;
    bool surv = false;
    if (t < tend) {
      float4 bb = bbn[t];
      surv = !(bb.z < tminx || bb.x > tmaxx || bb.w < tminy || bb.y > tmaxy);
    }
    unsigned long long m = __ballot(surv);
    int pre = __popcll(m & ((1ull << lane) - 1));
    __syncthreads();  // prior survivor-loop reads done before we overwrite
    if (lane == 0) s_wcnt[wid] = (int)__popcll(m);
    __syncthreads();
    int base = 0;
#pragma unroll
    for (int k = 0; k < 4; ++k)
      if (k < wid) base += s_wcnt[k];
    int total = s_wcnt[0] + s_wcnt[1] + s_wcnt[2] + s_wcnt[3];
    if (surv) {
      int dst = base + pre;
      const float4* src = trin + (size_t)t * 3;
      s_tri[dst * 3 + 0] = src[0];
      s_tri[dst * 3 + 1] = src[1];
      s_tri[dst * 3 + 2] = src[2];
    }
    __syncthreads();
    if (total > 0) {
      int last = total - 1;
      float4 c0 = s_tri[0], c1 = s_tri[1], c2 = s_tri[2];
      for (int u = 0; u < total; ++u) {
        int un = min(u + 1, last);
        const float4* Tn = &s_tri[un * 3];
        float4 n0 = Tn[0], n1 = Tn[1], n2 = Tn[2];   // 1-ahead prefetch
        float t0 = fmaf(px, c0.x, c0.z);
        float t1 = fmaf(px, c0.w, c1.y);
        float uu = fmaf(px, c2.x, c2.y);
        int ti = (int)c2.w;
        float tz = c1.w;
        // pixel A
        float W0 = fmaf(pyA, c0.y, t0);
        float W1 = fmaf(pyA, c1.x, t1);
        float W2 = (c1.z - W0) - W1;
        float zi = fmaf(pyA, c2.z, uu);
        float mw = fminf(W0, fminf(W1, W2));
        float d = zi - bA;
        float sl = tz + btA;
        bool upd = (mw >= TOLW) & (d > sl);
        bool cont = (mw >= -TOLW) & (d > -sl);
        flA = flA | (cont & !upd);
        if (upd) { bA = zi; btA = tz; iA = ti; }
        // pixel B
        W0 = fmaf(pyB, c0.y, t0);
        W1 = fmaf(pyB, c1.x, t1);
        W2 = (c1.z - W0) - W1;
        zi = fmaf(pyB, c2.z, uu);
        mw = fminf(W0, fminf(W1, W2));
        d = zi - bB;
        sl = tz + btB;
        upd = (mw >= TOLW) & (d > sl);
        cont = (mw >= -TOLW) & (d > -sl);
        flB = flB | (cont & !upd);
        if (upd) { bB = zi; btB = tz; iB = ti; }
        c0 = n0; c1 = n1; c2 = n2;
      }
    }
  }
  size_t NHW = (size_t)gridDim.z / SPLIT * IMG_H * IMG_W;
  size_t gA = (size_t)n * IMG_H * IMG_W + (size_t)yA * IMG_W + x;
  size_t gB = (size_t)n * IMG_H * IMG_W + (size_t)yB * IMG_W + x;
  zpart[(size_t)s * NHW + gA] = bA;
  tpart[(size_t)s * NHW + gA] = btA;
  ipart[(size_t)s * NHW + gA] = (iA + 1) | (flA ? (1 << 30) : 0);
  zpart[(size_t)s * NHW + gB] = bB;
  tpart[(size_t)s * NHW + gB] = btB;
  ipart[(size_t)s * NHW + gB] = (iB + 1) | (flB ? (1 << 30) : 0);
}

// ---------------------------------------------------------------------------
// Kernel 3b: merge SPLIT partials with tolerance. Clean separation -> write
// winner; any ambiguity or raster flag -> append pixel to fix list.
// ---------------------------------------------------------------------------
__global__ __launch_bounds__(256) void k_resolve(
    const float* __restrict__ zpart,
    const float* __restrict__ tpart,
    const int* __restrict__ ipart,
    float* __restrict__ out_idx,
    int* __restrict__ list,
    int* __restrict__ count,
    int NHW) {
  int gid = blockIdx.x * blockDim.x + threadIdx.x;
  if (gid >= NHW) return;
  float z0 = zpart[gid], z1 = zpart[(size_t)NHW + gid];
  float t0 = tpart[gid], t1 = tpart[(size_t)NHW + gid];
  int e0 = ipart[gid], e1 = ipart[(size_t)NHW + gid];
  bool fl = (((e0 | e1) >> 30) & 1) != 0;
  int i0 = (e0 & 0x3FFFFFFF) - 1;
  int i1 = (e1 & 0x3FFFFFFF) - 1;
  float ts = t0 + t1;
  bool bothEmpty = (i0 < 0) & (i1 < 0);
  bool amb = fl | ((fabsf(z1 - z0) <= ts) & !bothEmpty);
  if (!amb) {
    out_idx[gid] = (float)((z1 > z0) ? i1 : i0);
  } else {
    int slot = atomicAdd(count, 1);
    list[slot] = gid;
  }
}

// ---------------------------------------------------------------------------
// Kernel 3c: exact f64 fallback. One wave per flagged pixel (grid-stride);
// lanes stride the full F triangles with the trusted R9 f64 math, then a
// shuffle reduction: max zi, exact tie -> min index (reference tie-break).
// ---------------------------------------------------------------------------
__global__ __launch_bounds__(256) void k_fix(
    const double2* __restrict__ tri,
    const int* __restrict__ list,
    const int* __restrict__ count,
    float* __restrict__ out_idx,
    int F) {
  int nfl = *count;
  int nwaves = (gridDim.x * blockDim.x) >> 6;
  int wave = (blockIdx.x * blockDim.x + threadIdx.x) >> 6;
  int lane = threadIdx.x & 63;
  const int HW = IMG_H * IMG_W;
  for (int w = wave; w < nfl; w += nwaves) {
    int gid = list[w];
    int n = gid / HW;
    int p = gid - n * HW;
    double px = (double)(p % IMG_W);
    double py = (double)(p / IMG_W);
    const double2* trin = tri + (size_t)n * F * 6;
    double bz = EPSD;
    int bi = -1;
    for (int t = lane; t < F; t += 64) {
      const double2* T = trin + (size_t)t * 6;
      double2 q0 = T[0], q1 = T[1], q2 = T[2], q3 = T[3], q4 = T[4], q5 = T[5];
      double W0 = fma(py, q0.y, fma(px, q0.x, q1.x));
      double W1 = fma(py, q2.x, fma(px, q1.y, q2.y));
      double W2 = fma(py, q3.y, fma(px, q3.x, q4.x));
      double zi = fma(py, q5.y, fma(px, q4.y, q5.x));
      if ((W0 >= 0.0) & (W1 >= 0.0) & (W2 >= 0.0) & (zi > bz)) { bz = zi; bi = t; }
    }
#pragma unroll
    for (int o = 1; o < 64; o <<= 1) {
      double oz = __shfl_xor(bz, o);
      int oi = __shfl_xor(bi, o);
      if ((oz > bz) || ((oz == bz) && ((unsigned)oi < (unsigned)bi))) {
        bz = oz; bi = oi;
      }
    }
    if (lane == 0) out_idx[gid] = (float)bi;
  }
}

// ---------------------------------------------------------------------------
// Kernel 4: interpolation + bilinear texture sample + remaining outputs.
// ---------------------------------------------------------------------------
__global__ __launch_bounds__(256) void k_interp(
    const double* __restrict__ vpixd,
    const float* __restrict__ vt,
    const int* __restrict__ vi,
    const int* __restrict__ vti,
    const float* __restrict__ tex,
    float* __restrict__ out,
    int N, int V) {
#pragma clang fp contract(off)
  const int HW = IMG_H * IMG_W;
  int gid = blockIdx.x * blockDim.x + threadIdx.x;
  if (gid >= N * HW) return;
  int n = gid / HW;
  int p = gid - n * HW;
  int y = p / IMG_W;
  int x = p - y * IMG_W;
  size_t NHW = (size_t)N * HW;
  float* out_render = out;             // (N,3,H,W)
  float* out_mask = out + 3 * NHW;     // (N,H,W)
  float* out_depth = out + 4 * NHW;    // (N,H,W)
  float* out_vt = out + 5 * NHW;       // (N,H,W,2)
  float* out_bary = out + 7 * NHW;     // (N,3,H,W)
  float* out_idx = out + 10 * NHW;     // (N,H,W) written by k_resolve/k_fix

  int idx = (int)out_idx[gid];
  if (idx < 0) {
    for (int c = 0; c < 3; ++c) out_render[(size_t)(n * 3 + c) * HW + p] = 0.0f;
    out_mask[gid] = 0.0f;
    out_depth[gid] = 0.0f;
    out_vt[(size_t)gid * 2 + 0] = 0.0f;
    out_vt[(size_t)gid * 2 + 1] = 0.0f;
    for (int k = 0; k < 3; ++k) out_bary[(size_t)(n * 3 + k) * HW + p] = 0.0f;
    return;
  }
  int f0 = vi[idx * 3 + 0], f1 = vi[idx * 3 + 1], f2 = vi[idx * 3 + 2];
  int t0i = vti[idx * 3 + 0], t1i = vti[idx * 3 + 1], t2i = vti[idx * 3 + 2];
  const double* pv0 = vpixd + ((size_t)n * V + f0) * 3;
  const double* pv1 = vpixd + ((size_t)n * V + f1) * 3;
  const double* pv2 = vpixd + ((size_t)n * V + f2) * 3;
  float x0 = (float)pv0[0], y0 = (float)pv0[1], z0 = (float)pv0[2];
  float x1 = (float)pv1[0], y1 = (float)pv1[1], z1 = (float)pv1[2];
  float x2 = (float)pv2[0], y2 = (float)pv2[1], z2 = (float)pv2[2];
  float px = (float)x, py = (float)y;
  float w0 = (px - x1) * (y2 - y1) - (py - y1) * (x2 - x1);
  float w1 = (px - x2) * (y0 - y2) - (py - y2) * (x0 - x2);
  float w2 = (px - x0) * (y1 - y0) - (py - y0) * (x1 - x0);
  float area = (x2 - x0) * (y1 - y0) - (y2 - y0) * (x1 - x0);
  float sa = (fabsf(area) > EPSF) ? area : 1.0f;
  float b0 = w0 / sa, b1 = w1 / sa, b2 = w2 / sa;
  float zz0 = fmaxf(z0, EPSF), zz1 = fmaxf(z1, EPSF), zz2 = fmaxf(z2, EPSF);
  float bz0 = b0 / zz0, bz1 = b1 / zz1, bz2 = b2 / zz2;
  float zi = fmaxf((bz0 + bz1) + bz2, EPSF);
  float r0 = bz0 / zi, r1 = bz1 / zi, r2 = bz2 / zi;
  float depth = 1.0f / zi;
  float u0 = vt[(size_t)t0i * 2 + 0], q0 = 1.0f - vt[(size_t)t0i * 2 + 1];
  float u1 = vt[(size_t)t1i * 2 + 0], q1 = 1.0f - vt[(size_t)t1i * 2 + 1];
  float u2 = vt[(size_t)t2i * 2 + 0], q2 = 1.0f - vt[(size_t)t2i * 2 + 1];
  float vtx = (r0 * u0 + r1 * u1) + r2 * u2;
  float vty = (r0 * q0 + r1 * q1) + r2 * q2;
  float gx = vtx * 2.0f - 1.0f;
  float gy = vty * 2.0f - 1.0f;
  float ix = ((gx + 1.0f) * 0.5f) * (float)TEX_W - 0.5f;
  float iy = ((gy + 1.0f) * 0.5f) * (float)TEX_H - 0.5f;
  float x0f = floorf(ix), y0f = floorf(iy);
  float fx = ix - x0f, fy = iy - y0f;
  int x0i = min(max((int)x0f, 0), TEX_W - 1);
  int x1i = min(max((int)x0f + 1, 0), TEX_W - 1);
  int y0i = min(max((int)y0f, 0), TEX_H - 1);
  int y1i = min(max((int)y0f + 1, 0), TEX_H - 1);
  float omfx = 1.0f - fx, omfy = 1.0f - fy;
  for (int c = 0; c < 3; ++c) {
    const float* tc = tex + (size_t)(n * 3 + c) * TEX_H * TEX_W;
    float v00 = tc[(size_t)y0i * TEX_W + x0i];
    float v01 = tc[(size_t)y0i * TEX_W + x1i];
    float v10 = tc[(size_t)y1i * TEX_W + x0i];
    float v11 = tc[(size_t)y1i * TEX_W + x1i];
    float o = (v00 * omfx + v01 * fx) * omfy + (v10 * omfx + v11 * fx) * fy;
    out_render[(size_t)(n * 3 + c) * HW + p] = o;
  }
  out_mask[gid] = 1.0f;
  out_depth[gid] = depth;
  out_vt[(size_t)gid * 2 + 0] = vtx;
  out_vt[(size_t)gid * 2 + 1] = vty;
  out_bary[(size_t)(n * 3 + 0) * HW + p] = r0;
  out_bary[(size_t)(n * 3 + 1) * HW + p] = r1;
  out_bary[(size_t)(n * 3 + 2) * HW + p] = r2;
}

// ---------------------------------------------------------------------------
extern "C" void kernel_launch(void* const* d_in, const int* in_sizes, int n_in,
                              void* d_out, int out_size, void* d_ws, size_t ws_size,
                              hipStream_t stream) {
  const float* v = (const float*)d_in[0];
  const float* tex = (const float*)d_in[1];
  const float* vt = (const float*)d_in[2];
  const int* vi = (const int*)d_in[3];
  const int* vti = (const int*)d_in[4];
  const float* campos = (const float*)d_in[5];
  const float* camrot = (const float*)d_in[6];
  const float* focal = (const float*)d_in[7];
  const float* princpt = (const float*)d_in[8];
  int N = in_sizes[5] / 3;            // campos (N,3)
  int V = in_sizes[0] / (3 * N);      // v (N,V,3)
  int F = in_sizes[3] / 3;            // vi (F,3)

  char* wp = (char*)d_ws;
  double* vpixd = (double*)wp;
  wp += sizeof(double) * (size_t)N * V * 3;      // 196608 B
  double2* tri = (double2*)wp;
  wp += sizeof(double2) * (size_t)N * F * 6;     // 393216 B
  float4* bbox = (float4*)wp;
  wp += sizeof(float4) * (size_t)N * F;          //  65536 B
  float4* trif = (float4*)wp;
  wp += sizeof(float4) * (size_t)N * F * 3;      // 196608 B
  int* d_count = (int*)wp;                       //      4 B

  const int HW = IMG_H * IMG_W;
  const size_t NHW = (size_t)N * HW;
  // Scratch carved from d_out slices 0..6 (7*NHW*4 = 14,680,064 B):
  //   zpart (SPLIT*NHW*4) + tpart (same) + ipart (same) = 12,582,912
  //   fix list (NHW*4)                                  =  2,097,152
  // k_interp rewrites those slices only AFTER k_resolve/k_fix consumed them.
  float* zpart = (float*)d_out;
  float* tpart = (float*)d_out + SPLIT * NHW;
  int* ipart = (int*)d_out + 2 * SPLIT * NHW;
  int* list = (int*)d_out + 3 * SPLIT * NHW;
  float* out_idx = (float*)d_out + (size_t)10 * NHW;

  int nv = N * V;
  k_project<<<(nv + 255) / 256, 256, 0, stream>>>(v, campos, camrot, focal,
                                                  princpt, vpixd, N, V);
  int nf = N * F;
  k_setup<<<(nf + 255) / 256, 256, 0, stream>>>(vpixd, vi, tri, trif, bbox,
                                                N, V, F);
  dim3 rgrid(IMG_W / 16, IMG_H / 32, N * SPLIT);
  dim3 rblock(16, 16, 1);
  k_raster<<<rgrid, rblock, 0, stream>>>(trif, bbox, zpart, tpart, ipart, F);
  hipMemsetAsync(d_count, 0, sizeof(int), stream);
  k_resolve<<<((int)NHW + 255) / 256, 256, 0, stream>>>(
      zpart, tpart, ipart, out_idx, list, d_count, (int)NHW);
  k_fix<<<120, 256, 0, stream>>>(tri, list, d_count, out_idx, F);
  int np = N * HW;
  k_interp<<<(np + 255) / 256, 256, 0, stream>>>(vpixd, vt, vi, vti, tex,
                                                 (float*)d_out, N, V);
}

// Round 11
// 307.984 us; speedup vs baseline: 1.3305x; 1.3305x over previous
//
#include <hip/hip_runtime.h>
#include <math.h>

#define EPSD 1e-8
#define EPSF 1e-8f
#define TOLW 1e-5f
#define IMG_H 512
#define IMG_W 512
#define TEX_W 1024
#define TEX_H 1024
#define RCH 256    // triangles per compaction chunk
#define SPLIT 2    // triangle-dimension split per tile

// ---------------------------------------------------------------------------
// Kernel 1: project vertices in f64 -> vpixd (x_pix, y_pix, z_cam)
// ---------------------------------------------------------------------------
__global__ __launch_bounds__(256) void k_project(
    const float* __restrict__ v,
    const float* __restrict__ campos,
    const float* __restrict__ camrot,
    const float* __restrict__ focal,
    const float* __restrict__ princpt,
    double* __restrict__ vpixd,
    int N, int V) {
#pragma clang fp contract(off)
  int i = blockIdx.x * blockDim.x + threadIdx.x;
  if (i >= N * V) return;
  int n = i / V;
  const float* vv = v + (size_t)i * 3;
  double ax = (double)vv[0] - (double)campos[n * 3 + 0];
  double ay = (double)vv[1] - (double)campos[n * 3 + 1];
  double az = (double)vv[2] - (double)campos[n * 3 + 2];
  const float* R = camrot + (size_t)n * 9;
  double cx = ((double)R[0] * ax + (double)R[1] * ay) + (double)R[2] * az;
  double cy = ((double)R[3] * ax + (double)R[4] * ay) + (double)R[5] * az;
  double cz = ((double)R[6] * ax + (double)R[7] * ay) + (double)R[8] * az;
  double zz = fmax(cz, EPSD);
  double xd = cx / zz;
  double yd = cy / zz;
  const float* Fc = focal + (size_t)n * 4;
  double px = ((double)Fc[0] * xd + (double)Fc[1] * yd) + (double)princpt[n * 2 + 0];
  double py = ((double)Fc[2] * xd + (double)Fc[3] * yd) + (double)princpt[n * 2 + 1];
  vpixd[(size_t)i * 3 + 0] = px;
  vpixd[(size_t)i * 3 + 1] = py;
  vpixd[(size_t)i * 3 + 2] = cz;
}

// ---------------------------------------------------------------------------
// Kernel 2: per-triangle setup. Emits:
//  (a) exact f64 coeffs (k_fix fallback):
//      T[0]=(EA0,EB0) T[1]=(EC0,EA1) T[2]=(EB1,EC1) T[3]=(EA2,EB2)
//      T[4]=(EC2,P)  T[5]=(Q,S)
//  (b) f32 filter pack, PER-EDGE normalized (4 x float4):
//      q0=[a0,b0,c0,a1] q1=[b1,c1,a2,b2] q2=[c2,tz,P,Q] q3=[S,idx,0,0]
//      a_k,b_k,c_k = EA_k*g_k, EB_k*g_k, EC_k*g_k with g_k = 1/m_k,
//      m_k = 512(|EA_k|+|EB_k|)+|EC_k|. Vertices lie in [0,512]^2 so
//      |EC_k| <= 512(|EA_k|+|EB_k|) -> normalized gradient >= 1/1024/px ->
//      the +-TOLW uncertainty band is <= ~1e-2 px for EVERY edge (the R10
//      shared-scale pack inflated weak-edge bands 10-100x -> 5% flag rate).
//      f32 eval error of W_k <= ~3e-7 << TOLW. tz = 2e-6*(512(|P|+|S|)+|Q|)
//      bounds the f32 zi error (~10x margin).
// ---------------------------------------------------------------------------
__global__ __launch_bounds__(256) void k_setup(
    const double* __restrict__ vpixd,
    const int* __restrict__ vi,
    double2* __restrict__ tri,
    float4* __restrict__ trif,
    float4* __restrict__ bbox,
    int N, int V, int F) {
#pragma clang fp contract(off)
  int i = blockIdx.x * blockDim.x + threadIdx.x;
  if (i >= N * F) return;
  int n = i / F;
  int f = i - n * F;
  int i0 = vi[f * 3 + 0], i1 = vi[f * 3 + 1], i2 = vi[f * 3 + 2];
  const double* p0 = vpixd + ((size_t)n * V + i0) * 3;
  const double* p1 = vpixd + ((size_t)n * V + i1) * 3;
  const double* p2 = vpixd + ((size_t)n * V + i2) * 3;
  double x0 = p0[0], y0 = p0[1], z0 = p0[2];
  double x1 = p1[0], y1 = p1[1], z1 = p1[2];
  double x2 = p2[0], y2 = p2[1], z2 = p2[2];
  double A0 = y2 - y1, B0 = x2 - x1;
  double A1 = y0 - y2, B1 = x0 - x2;
  double A2 = y1 - y0, B2 = x1 - x0;
  double area = (x2 - x0) * A2 - (y2 - y0) * B2;
  bool valid = (fabs(area) > EPSD) && (z0 > EPSD) && (z1 > EPSD) && (z2 > EPSD);
  double s = area;
  double EA0 = 0.0, EB0 = 0.0, EC0 = -1.0;
  double EA1 = 0.0, EB1 = 0.0, EC1 = -1.0;
  double EA2 = 0.0, EB2 = 0.0, EC2 = -1.0;
  double P = 0.0, Q = 0.0, S = 0.0;
  float4 f0v = make_float4(0.f, 0.f, -1.f, 0.f);
  float4 f1v = make_float4(0.f, -1.f, 0.f, 0.f);
  float4 f2v = make_float4(-1.f, 0.f, 0.f, 0.f);
  float4 f3v = make_float4(0.f, (float)f, 0.f, 0.f);
  if (valid) {
    EA0 = A0 * s; EB0 = -(B0 * s); EC0 = (y1 * B0 - x1 * A0) * s;
    EA1 = A1 * s; EB1 = -(B1 * s); EC1 = (y2 * B1 - x2 * A1) * s;
    EA2 = A2 * s; EB2 = -(B2 * s); EC2 = (y0 * B2 - x0 * A2) * s;
    double s2 = s * s;
    double R0 = 1.0 / (s2 * fmax(z0, EPSD));
    double R1 = 1.0 / (s2 * fmax(z1, EPSD));
    double R2 = 1.0 / (s2 * fmax(z2, EPSD));
    P = EA0 * R0 + EA1 * R1 + EA2 * R2;
    S = EB0 * R0 + EB1 * R1 + EB2 * R2;
    Q = EC0 * R0 + EC1 * R1 + EC2 * R2;
    double g0 = 1.0 / (512.0 * (fabs(EA0) + fabs(EB0)) + fabs(EC0));
    double g1 = 1.0 / (512.0 * (fabs(EA1) + fabs(EB1)) + fabs(EC1));
    double g2 = 1.0 / (512.0 * (fabs(EA2) + fabs(EB2)) + fabs(EC2));
    double D = 512.0 * (fabs(P) + fabs(S)) + fabs(Q);
    f0v = make_float4((float)(EA0 * g0), (float)(EB0 * g0), (float)(EC0 * g0),
                      (float)(EA1 * g1));
    f1v = make_float4((float)(EB1 * g1), (float)(EC1 * g1),
                      (float)(EA2 * g2), (float)(EB2 * g2));
    f2v = make_float4((float)(EC2 * g2), (float)(2.0e-6 * D),
                      (float)P, (float)Q);
    f3v = make_float4((float)S, (float)f, 0.f, 0.f);
  }
  double2* T = tri + (size_t)i * 6;
  T[0] = make_double2(EA0, EB0);
  T[1] = make_double2(EC0, EA1);
  T[2] = make_double2(EB1, EC1);
  T[3] = make_double2(EA2, EB2);
  T[4] = make_double2(EC2, P);
  T[5] = make_double2(Q, S);
  float4* Tf = trif + (size_t)i * 4;
  Tf[0] = f0v; Tf[1] = f1v; Tf[2] = f2v; Tf[3] = f3v;
  float mnx = (float)fmin(x0, fmin(x1, x2));
  float mny = (float)fmin(y0, fmin(y1, y2));
  float mxx = (float)fmax(x0, fmax(x1, x2));
  float mxy = (float)fmax(y0, fmax(y1, y2));
  bbox[i] = make_float4(mnx, mny, mxx, mxy);
}

// ---------------------------------------------------------------------------
// Kernel 3: f32-filtered tiled rasterizer with final-margin flagging.
// 16x32-px tile / 2 px per thread, triangle split (SPLIT=2). Per chunk:
// ordered ballot/prefix compaction of survivors' 4-quad packs into LDS.
// Update rule: strong (mw>=TOLW) & zi>best wins. Every non-winning weak
// candidate (and every displaced best) feeds a threat accumulator
// thr=max(zi+tz); pixel flagged iff thr >= best - tz_best at the END
// (R10's sticky running-best flag massively over-flagged).
// ---------------------------------------------------------------------------
__global__ __launch_bounds__(256, 8) void k_raster(
    const float4* __restrict__ trif,
    const float4* __restrict__ bbox,
    float* __restrict__ zpart,
    float* __restrict__ tpart,
    int* __restrict__ ipart,
    int F) {
  __shared__ float4 s_tri[RCH * 4];    // 16384 B
  __shared__ int s_wcnt[4];
  int nz = blockIdx.z;
  int n = nz / SPLIT;
  int s = nz - n * SPLIT;
  int x = blockIdx.x * 16 + threadIdx.x;
  int yA = blockIdx.y * 32 + threadIdx.y;
  int yB = yA + 16;
  float px = (float)x;
  float pyA = (float)yA, pyB = (float)yB;
  float tminx = (float)(blockIdx.x * 16) - 0.5f;   // 0.5px guard band
  float tmaxx = tminx + 16.0f;
  float tminy = (float)(blockIdx.y * 32) - 0.5f;
  float tmaxy = tminy + 32.0f;
  int tid = threadIdx.y * 16 + threadIdx.x;
  int wid = tid >> 6, lane = tid & 63;
  float bA = EPSF, bB = EPSF;       // zi > EPS folded into strict->
  float tA = 0.0f, tB = 0.0f;
  float thA = -1e30f, thB = -1e30f; // threat accumulators
  int iA = -1, iB = -1;
  const float4* trin = trif + (size_t)n * F * 4;
  const float4* bbn = bbox + (size_t)n * F;
  int half = (F + SPLIT - 1) / SPLIT;
  int tbeg = s * half;
  int tend = min(F, tbeg + half);

  for (int c = tbeg; c < tend; c += RCH) {
    int t = c + tid;
    bool surv = false;
    if (t < tend) {
      float4 bb = bbn[t];
      surv = !(bb.z < tminx || bb.x > tmaxx || bb.w < tminy || bb.y > tmaxy);
    }
    unsigned long long m = __ballot(surv);
    int pre = __popcll(m & ((1ull << lane) - 1));
    __syncthreads();  // prior survivor-loop reads done before we overwrite
    if (lane == 0) s_wcnt[wid] = (int)__popcll(m);
    __syncthreads();
    int base = 0;
#pragma unroll
    for (int k = 0; k < 4; ++k)
      if (k < wid) base += s_wcnt[k];
    int total = s_wcnt[0] + s_wcnt[1] + s_wcnt[2] + s_wcnt[3];
    if (surv) {
      int dst = base + pre;
      const float4* src = trin + (size_t)t * 4;
      s_tri[dst * 4 + 0] = src[0];
      s_tri[dst * 4 + 1] = src[1];
      s_tri[dst * 4 + 2] = src[2];
      s_tri[dst * 4 + 3] = src[3];
    }
    __syncthreads();
    if (total > 0) {
      int last = total - 1;
      float4 c0 = s_tri[0], c1 = s_tri[1], c2 = s_tri[2], c3 = s_tri[3];
      for (int u = 0; u < total; ++u) {
        int un = min(u + 1, last);
        const float4* Tn = &s_tri[un * 4];
        float4 n0 = Tn[0], n1 = Tn[1];           // 1-ahead prefetch, half 1
        float tpx0 = fmaf(px, c0.x, c0.z);
        float tpx1 = fmaf(px, c0.w, c1.y);
        float tpx2 = fmaf(px, c1.z, c2.x);
        float tzi = fmaf(px, c2.z, c2.w);
        float tz = c2.y;
        int ti = (int)c3.y;
        float Sc = c3.x;
        float4 n2 = Tn[2], n3 = Tn[3];           // prefetch, half 2
        // pixel A
        float W0 = fmaf(pyA, c0.y, tpx0);
        float W1 = fmaf(pyA, c1.x, tpx1);
        float W2 = fmaf(pyA, c1.w, tpx2);
        float zi = fmaf(pyA, Sc, tzi);
        float mw = fminf(W0, fminf(W1, W2));
        bool strong = mw >= TOLW;
        bool weak = mw >= -TOLW;
        bool upd = strong & (zi > bA);
        float tv = upd ? (bA + tA) : (weak ? (zi + tz) : -1e30f);
        thA = fmaxf(thA, tv);
        if (upd) { bA = zi; tA = tz; iA = ti; }
        // pixel B
        W0 = fmaf(pyB, c0.y, tpx0);
        W1 = fmaf(pyB, c1.x, tpx1);
        W2 = fmaf(pyB, c1.w, tpx2);
        zi = fmaf(pyB, Sc, tzi);
        mw = fminf(W0, fminf(W1, W2));
        strong = mw >= TOLW;
        weak = mw >= -TOLW;
        upd = strong & (zi > bB);
        tv = upd ? (bB + tB) : (weak ? (zi + tz) : -1e30f);
        thB = fmaxf(thB, tv);
        if (upd) { bB = zi; tB = tz; iB = ti; }
        c0 = n0; c1 = n1; c2 = n2; c3 = n3;
      }
    }
  }
  bool flA = thA >= (bA - tA);
  bool flB = thB >= (bB - tB);
  size_t NHW = (size_t)gridDim.z / SPLIT * IMG_H * IMG_W;
  size_t gA = (size_t)n * IMG_H * IMG_W + (size_t)yA * IMG_W + x;
  size_t gB = (size_t)n * IMG_H * IMG_W + (size_t)yB * IMG_W + x;
  zpart[(size_t)s * NHW + gA] = bA;
  tpart[(size_t)s * NHW + gA] = tA;
  ipart[(size_t)s * NHW + gA] = (iA + 1) | (flA ? (1 << 30) : 0);
  zpart[(size_t)s * NHW + gB] = bB;
  tpart[(size_t)s * NHW + gB] = tB;
  ipart[(size_t)s * NHW + gB] = (iB + 1) | (flB ? (1 << 30) : 0);
}

// ---------------------------------------------------------------------------
// Kernel 3b: merge SPLIT partials with tolerance. Clean separation -> write
// winner; any ambiguity or raster flag -> append pixel to fix list.
// ---------------------------------------------------------------------------
__global__ __launch_bounds__(256) void k_resolve(
    const float* __restrict__ zpart,
    const float* __restrict__ tpart,
    const int* __restrict__ ipart,
    float* __restrict__ out_idx,
    int* __restrict__ list,
    int* __restrict__ count,
    int NHW) {
  int gid = blockIdx.x * blockDim.x + threadIdx.x;
  if (gid >= NHW) return;
  float z0 = zpart[gid], z1 = zpart[(size_t)NHW + gid];
  float t0 = tpart[gid], t1 = tpart[(size_t)NHW + gid];
  int e0 = ipart[gid], e1 = ipart[(size_t)NHW + gid];
  bool fl = (((e0 | e1) >> 30) & 1) != 0;
  int i0 = (e0 & 0x3FFFFFFF) - 1;
  int i1 = (e1 & 0x3FFFFFFF) - 1;
  float ts = t0 + t1;
  bool bothEmpty = (i0 < 0) & (i1 < 0);
  bool amb = fl | ((fabsf(z1 - z0) <= ts) & !bothEmpty);
  if (!amb) {
    out_idx[gid] = (float)((z1 > z0) ? i1 : i0);
  } else {
    int slot = atomicAdd(count, 1);
    list[slot] = gid;
  }
}

// ---------------------------------------------------------------------------
// Kernel 3c: exact f64 fallback. One wave per flagged pixel (grid-stride);
// lanes stride the full F triangles with trusted f64 math, then a shuffle
// reduction: max zi, exact tie -> min index (reference tie-break).
// ---------------------------------------------------------------------------
__global__ __launch_bounds__(256) void k_fix(
    const double2* __restrict__ tri,
    const int* __restrict__ list,
    const int* __restrict__ count,
    float* __restrict__ out_idx,
    int F) {
  int nfl = *count;
  int nwaves = (gridDim.x * blockDim.x) >> 6;
  int wave = (blockIdx.x * blockDim.x + threadIdx.x) >> 6;
  int lane = threadIdx.x & 63;
  const int HW = IMG_H * IMG_W;
  for (int w = wave; w < nfl; w += nwaves) {
    int gid = list[w];
    int n = gid / HW;
    int p = gid - n * HW;
    double px = (double)(p % IMG_W);
    double py = (double)(p / IMG_W);
    const double2* trin = tri + (size_t)n * F * 6;
    double bz = EPSD;
    int bi = -1;
    for (int t = lane; t < F; t += 64) {
      const double2* T = trin + (size_t)t * 6;
      double2 q0 = T[0], q1 = T[1], q2 = T[2], q3 = T[3], q4 = T[4], q5 = T[5];
      double W0 = fma(py, q0.y, fma(px, q0.x, q1.x));
      double W1 = fma(py, q2.x, fma(px, q1.y, q2.y));
      double W2 = fma(py, q3.y, fma(px, q3.x, q4.x));
      double zi = fma(py, q5.y, fma(px, q4.y, q5.x));
      if ((W0 >= 0.0) & (W1 >= 0.0) & (W2 >= 0.0) & (zi > bz)) { bz = zi; bi = t; }
    }
#pragma unroll
    for (int o = 1; o < 64; o <<= 1) {
      double oz = __shfl_xor(bz, o);
      int oi = __shfl_xor(bi, o);
      if ((oz > bz) || ((oz == bz) && ((unsigned)oi < (unsigned)bi))) {
        bz = oz; bi = oi;
      }
    }
    if (lane == 0) out_idx[gid] = (float)bi;
  }
}

// ---------------------------------------------------------------------------
// Kernel 4: interpolation + bilinear texture sample + remaining outputs.
// ---------------------------------------------------------------------------
__global__ __launch_bounds__(256) void k_interp(
    const double* __restrict__ vpixd,
    const float* __restrict__ vt,
    const int* __restrict__ vi,
    const int* __restrict__ vti,
    const float* __restrict__ tex,
    float* __restrict__ out,
    int N, int V) {
#pragma clang fp contract(off)
  const int HW = IMG_H * IMG_W;
  int gid = blockIdx.x * blockDim.x + threadIdx.x;
  if (gid >= N * HW) return;
  int n = gid / HW;
  int p = gid - n * HW;
  int y = p / IMG_W;
  int x = p - y * IMG_W;
  size_t NHW = (size_t)N * HW;
  float* out_render = out;             // (N,3,H,W)
  float* out_mask = out + 3 * NHW;     // (N,H,W)
  float* out_depth = out + 4 * NHW;    // (N,H,W)
  float* out_vt = out + 5 * NHW;       // (N,H,W,2)
  float* out_bary = out + 7 * NHW;     // (N,3,H,W)
  float* out_idx = out + 10 * NHW;     // (N,H,W) written by k_resolve/k_fix

  int idx = (int)out_idx[gid];
  if (idx < 0) {
    for (int c = 0; c < 3; ++c) out_render[(size_t)(n * 3 + c) * HW + p] = 0.0f;
    out_mask[gid] = 0.0f;
    out_depth[gid] = 0.0f;
    out_vt[(size_t)gid * 2 + 0] = 0.0f;
    out_vt[(size_t)gid * 2 + 1] = 0.0f;
    for (int k = 0; k < 3; ++k) out_bary[(size_t)(n * 3 + k) * HW + p] = 0.0f;
    return;
  }
  int f0 = vi[idx * 3 + 0], f1 = vi[idx * 3 + 1], f2 = vi[idx * 3 + 2];
  int t0i = vti[idx * 3 + 0], t1i = vti[idx * 3 + 1], t2i = vti[idx * 3 + 2];
  const double* pv0 = vpixd + ((size_t)n * V + f0) * 3;
  const double* pv1 = vpixd + ((size_t)n * V + f1) * 3;
  const double* pv2 = vpixd + ((size_t)n * V + f2) * 3;
  float x0 = (float)pv0[0], y0 = (float)pv0[1], z0 = (float)pv0[2];
  float x1 = (float)pv1[0], y1 = (float)pv1[1], z1 = (float)pv1[2];
  float x2 = (float)pv2[0], y2 = (float)pv2[1], z2 = (float)pv2[2];
  float px = (float)x, py = (float)y;
  float w0 = (px - x1) * (y2 - y1) - (py - y1) * (x2 - x1);
  float w1 = (px - x2) * (y0 - y2) - (py - y2) * (x0 - x2);
  float w2 = (px - x0) * (y1 - y0) - (py - y0) * (x1 - x0);
  float area = (x2 - x0) * (y1 - y0) - (y2 - y0) * (x1 - x0);
  float sa = (fabsf(area) > EPSF) ? area : 1.0f;
  float b0 = w0 / sa, b1 = w1 / sa, b2 = w2 / sa;
  float zz0 = fmaxf(z0, EPSF), zz1 = fmaxf(z1, EPSF), zz2 = fmaxf(z2, EPSF);
  float bz0 = b0 / zz0, bz1 = b1 / zz1, bz2 = b2 / zz2;
  float zi = fmaxf((bz0 + bz1) + bz2, EPSF);
  float r0 = bz0 / zi, r1 = bz1 / zi, r2 = bz2 / zi;
  float depth = 1.0f / zi;
  float u0 = vt[(size_t)t0i * 2 + 0], q0 = 1.0f - vt[(size_t)t0i * 2 + 1];
  float u1 = vt[(size_t)t1i * 2 + 0], q1 = 1.0f - vt[(size_t)t1i * 2 + 1];
  float u2 = vt[(size_t)t2i * 2 + 0], q2 = 1.0f - vt[(size_t)t2i * 2 + 1];
  float vtx = (r0 * u0 + r1 * u1) + r2 * u2;
  float vty = (r0 * q0 + r1 * q1) + r2 * q2;
  float gx = vtx * 2.0f - 1.0f;
  float gy = vty * 2.0f - 1.0f;
  float ix = ((gx + 1.0f) * 0.5f) * (float)TEX_W - 0.5f;
  float iy = ((gy + 1.0f) * 0.5f) * (float)TEX_H - 0.5f;
  float x0f = floorf(ix), y0f = floorf(iy);
  float fx = ix - x0f, fy = iy - y0f;
  int x0i = min(max((int)x0f, 0), TEX_W - 1);
  int x1i = min(max((int)x0f + 1, 0), TEX_W - 1);
  int y0i = min(max((int)y0f, 0), TEX_H - 1);
  int y1i = min(max((int)y0f + 1, 0), TEX_H - 1);
  float omfx = 1.0f - fx, omfy = 1.0f - fy;
  for (int c = 0; c < 3; ++c) {
    const float* tc = tex + (size_t)(n * 3 + c) * TEX_H * TEX_W;
    float v00 = tc[(size_t)y0i * TEX_W + x0i];
    float v01 = tc[(size_t)y0i * TEX_W + x1i];
    float v10 = tc[(size_t)y1i * TEX_W + x0i];
    float v11 = tc[(size_t)y1i * TEX_W + x1i];
    float o = (v00 * omfx + v01 * fx) * omfy + (v10 * omfx + v11 * fx) * fy;
    out_render[(size_t)(n * 3 + c) * HW + p] = o;
  }
  out_mask[gid] = 1.0f;
  out_depth[gid] = depth;
  out_vt[(size_t)gid * 2 + 0] = vtx;
  out_vt[(size_t)gid * 2 + 1] = vty;
  out_bary[(size_t)(n * 3 + 0) * HW + p] = r0;
  out_bary[(size_t)(n * 3 + 1) * HW + p] = r1;
  out_bary[(size_t)(n * 3 + 2) * HW + p] = r2;
}

// ---------------------------------------------------------------------------
extern "C" void kernel_launch(void* const* d_in, const int* in_sizes, int n_in,
                              void* d_out, int out_size, void* d_ws, size_t ws_size,
                              hipStream_t stream) {
  const float* v = (const float*)d_in[0];
  const float* tex = (const float*)d_in[1];
  const float* vt = (const float*)d_in[2];
  const int* vi = (const int*)d_in[3];
  const int* vti = (const int*)d_in[4];
  const float* campos = (const float*)d_in[5];
  const float* camrot = (const float*)d_in[6];
  const float* focal = (const float*)d_in[7];
  const float* princpt = (const float*)d_in[8];
  int N = in_sizes[5] / 3;            // campos (N,3)
  int V = in_sizes[0] / (3 * N);      // v (N,V,3)
  int F = in_sizes[3] / 3;            // vi (F,3)

  char* wp = (char*)d_ws;
  double* vpixd = (double*)wp;
  wp += sizeof(double) * (size_t)N * V * 3;      // 196608 B
  double2* tri = (double2*)wp;
  wp += sizeof(double2) * (size_t)N * F * 6;     // 393216 B
  float4* bbox = (float4*)wp;
  wp += sizeof(float4) * (size_t)N * F;          //  65536 B
  float4* trif = (float4*)wp;
  wp += sizeof(float4) * (size_t)N * F * 4;      // 262144 B
  int* d_count = (int*)wp;                       //      4 B

  const int HW = IMG_H * IMG_W;
  const size_t NHW = (size_t)N * HW;
  // Scratch carved from d_out slices 0..6 (7*NHW*4 = 14,680,064 B):
  //   zpart/tpart/ipart (3 * SPLIT*NHW*4) + fix list (NHW*4) = 14,680,064 B.
  // k_interp rewrites those slices only AFTER k_resolve/k_fix consumed them.
  float* zpart = (float*)d_out;
  float* tpart = (float*)d_out + SPLIT * NHW;
  int* ipart = (int*)d_out + 2 * SPLIT * NHW;
  int* list = (int*)d_out + 3 * SPLIT * NHW;
  float* out_idx = (float*)d_out + (size_t)10 * NHW;

  int nv = N * V;
  k_project<<<(nv + 255) / 256, 256, 0, stream>>>(v, campos, camrot, focal,
                                                  princpt, vpixd, N, V);
  int nf = N * F;
  k_setup<<<(nf + 255) / 256, 256, 0, stream>>>(vpixd, vi, tri, trif, bbox,
                                                N, V, F);
  dim3 rgrid(IMG_W / 16, IMG_H / 32, N * SPLIT);
  dim3 rblock(16, 16, 1);
  k_raster<<<rgrid, rblock, 0, stream>>>(trif, bbox, zpart, tpart, ipart, F);
  hipMemsetAsync(d_count, 0, sizeof(int), stream);
  k_resolve<<<((int)NHW + 255) / 256, 256, 0, stream>>>(
      zpart, tpart, ipart, out_idx, list, d_count, (int)NHW);
  k_fix<<<240, 256, 0, stream>>>(tri, list, d_count, out_idx, F);
  int np = N * HW;
  k_interp<<<(np + 255) / 256, 256, 0, stream>>>(vpixd, vt, vi, vti, tex,
                                                 (float*)d_out, N, V);
}